// Round 6
// baseline (145.382 us; speedup 1.0000x reference)
//
#include <hip/hip_runtime.h>
#include <hip/hip_fp16.h>

#define SPB 4

// ---- helpers ----
__device__ __forceinline__ float rl(float v, int l) {
    return __builtin_bit_cast(float, __builtin_amdgcn_readlane(__builtin_bit_cast(int, v), l));
}
__device__ __forceinline__ float blo(unsigned d) { return __builtin_bit_cast(float, d << 16); }
__device__ __forceinline__ float bhi(unsigned d) { return __builtin_bit_cast(float, d & 0xffff0000u); }
__device__ __forceinline__ unsigned pack_bf16(float a, float b) {
    unsigned ua = __builtin_bit_cast(unsigned, a);
    unsigned ub = __builtin_bit_cast(unsigned, b);
    ua = (ua + 0x7fffu + ((ua >> 16) & 1u)) >> 16;   // RNE round to bf16
    ub = (ub + 0x7fffu + ((ub >> 16) & 1u)) >> 16;
    return ua | (ub << 16);
}

// ws layout (dword units):
// [0..191] C factors (3x64 f32), pad to 256,
// [256..8447] W0p (128x64 bf16-pairs), [8448..14591] Whp (3 x 32x64),
// [14592..16639] Wf1p (32x64), [16640..24831] W2f16 (32x256 f16-pairs = 32KB)
#define WS_C     0
#define WS_W0P   256
#define WS_WHP   (256 + 8192)
#define WS_WF1P  (256 + 8192 + 6144)
#define WS_W2F16 (256 + 8192 + 6144 + 2048)

__global__ __launch_bounds__(256) void preprocess(
    const float* __restrict__ embW1, const float* __restrict__ embW2,
    const float* __restrict__ outW0, const float* __restrict__ outWh,
    const float* __restrict__ outWf1, unsigned* __restrict__ ws)
{
    const int g = blockIdx.x * 256 + threadIdx.x;
    if (g < 8192) {                                  // W0p: [k2][f], k2 in [0,128)
        const int k2 = g >> 6, f = g & 63;
        ws[WS_W0P + g] = pack_bf16(outW0[(2*k2)*64 + f], outW0[(2*k2+1)*64 + f]);
    } else if (g < 14336) {                          // Whp: 3 layers of [k2][f], k2 in [0,32)
        const int i = g - 8192;
        const int layer = i >> 11, r = i & 2047;
        const int k2 = r >> 6, f = r & 63;
        const float* W = outWh + layer*4096;
        ws[WS_WHP + i] = pack_bf16(W[(2*k2)*64 + f], W[(2*k2+1)*64 + f]);
    } else if (g < 16384) {                          // Wf1p
        const int i = g - 14336;
        const int k2 = i >> 6, f = i & 63;
        ws[WS_WF1P + i] = pack_bf16(outWf1[(2*k2)*64 + f], outWf1[(2*k2+1)*64 + f]);
    } else if (g < 16576) {                          // C factors: r in [0,3), ch in [0,64)
        const int i = g - 16384;
        const int r = i >> 6, ch = i & 63;
        const float w0 = embW1[ch], w1 = embW1[64 + ch], w2 = embW1[128 + ch];
        float v;
        if (r == 0) {
            v = (1.f + 2.f*__cosf(0.01f*w0)) * (1.f + 2.f*__cosf(0.01f*w1))
              * (1.f + 2.f*__cosf(0.01f*w2)) * (1.f/27.f);
        } else if (r == 1) {
            v = (1.f + 2.f*(__cosf(0.025f*w0) + __cosf(0.05f*w0)))
              * (1.f + 2.f*(__cosf(0.025f*w1) + __cosf(0.05f*w1)))
              * (1.f + 2.f*(__cosf(0.025f*w2) + __cosf(0.05f*w2))) * (1.f/125.f);
        } else {
            v = (1.f + 2.f*(__cosf(0.03f*w0) + __cosf(0.06f*w0) + __cosf(0.09f*w0)))
              * (1.f + 2.f*(__cosf(0.03f*w1) + __cosf(0.06f*w1) + __cosf(0.09f*w1)))
              * (1.f + 2.f*(__cosf(0.03f*w2) + __cosf(0.06f*w2) + __cosf(0.09f*w2))) * (1.f/343.f);
        }
        ((float*)ws)[WS_C + i] = v;
    } else if (g < 24768) {                          // W2f16: [ch2][c], ch2 in [0,32), c in [0,256)
        const int i = g - 16576;
        const int ch2 = i >> 8, c = i & 255;
        __half2 h2 = __floats2half2_rn(embW2[(2*ch2)*256 + c], embW2[(2*ch2+1)*256 + c]);
        ws[WS_W2F16 + i] = __builtin_bit_cast(unsigned, h2);
    }
}

__global__ __launch_bounds__(256, 4) void model_fused(
    const float* __restrict__ x, const float* __restrict__ y, const float* __restrict__ t,
    const float* __restrict__ embW1, const float* __restrict__ embb1,
    const float* __restrict__ embwa, const float* __restrict__ embwb,
    const float* __restrict__ embb2,
    const float* __restrict__ mixW1, const float* __restrict__ mixb1,
    const float* __restrict__ mixwa, const float* __restrict__ mixwb,
    const float* __restrict__ mixW2, const float* __restrict__ mixb2,
    const float* __restrict__ outb0,
    const float* __restrict__ outwa0, const float* __restrict__ outwb0,
    const float* __restrict__ outbh,
    const float* __restrict__ outwah, const float* __restrict__ outwbh,
    const float* __restrict__ outbf1,
    const float* __restrict__ outwaf, const float* __restrict__ outwbf,
    const float* __restrict__ outWf2, const float* __restrict__ outbf2,
    const unsigned* __restrict__ ws,
    float* __restrict__ out, int N)
{
    __shared__ unsigned sW2[8192];    // embW2 f16-pairs, 32 KB
    __shared__ float se[SPB][256];    // mixer output e per sample
    __shared__ float hfin[SPB][64];   // final hidden for 64->3

    const int tid  = threadIdx.x;
    const int lane = tid & 63;
    const int wv   = tid >> 6;
    const int n0   = blockIdx.x * SPB;

    // ---- stage embW2 f16 into LDS: 8 independent dwordx4 loads issued up front ----
    {
        const uint4* g4 = (const uint4*)(ws + WS_W2F16);
        uint4* s4 = (uint4*)sW2;
        uint4 v0 = g4[tid       ], v1 = g4[tid +  256], v2 = g4[tid +  512], v3 = g4[tid +  768];
        uint4 v4 = g4[tid + 1024], v5 = g4[tid + 1280], v6 = g4[tid + 1536], v7 = g4[tid + 1792];
        s4[tid       ] = v0; s4[tid +  256] = v1; s4[tid +  512] = v2; s4[tid +  768] = v3;
        s4[tid + 1024] = v4; s4[tid + 1280] = v5; s4[tid + 1536] = v6; s4[tid + 1792] = v7;
    }

    // ---- phase 1: lane ch computes wave(u) for 4 samples (every wave duplicates) ----
    float swv0, swv1, swv2, swv3;
    {
        const float w0 = embW1[lane], w1 = embW1[64 + lane], w2 = embW1[128 + lane];
        const float bb = embb1[lane];
        const float ewa = embwa[0], ewb = embwb[0];
        const int ns0 = n0;
        const int ns1 = (n0 + 1 < N) ? n0 + 1 : N - 1;
        const int ns2 = (n0 + 2 < N) ? n0 + 2 : N - 1;
        const int ns3 = (n0 + 3 < N) ? n0 + 3 : N - 1;
        const float u0 = fmaf(x[ns0], w0, fmaf(y[ns0], w1, fmaf(t[ns0], w2, bb)));
        const float u1 = fmaf(x[ns1], w0, fmaf(y[ns1], w1, fmaf(t[ns1], w2, bb)));
        const float u2 = fmaf(x[ns2], w0, fmaf(y[ns2], w1, fmaf(t[ns2], w2, bb)));
        const float u3 = fmaf(x[ns3], w0, fmaf(y[ns3], w1, fmaf(t[ns3], w2, bb)));
        swv0 = ewa*__sinf(u0) + ewb*__cosf(u0);
        swv1 = ewa*__sinf(u1) + ewb*__cosf(u1);
        swv2 = ewa*__sinf(u2) + ewb*__cosf(u2);
        swv3 = ewa*__sinf(u3) + ewb*__cosf(u3);
    }
    __syncthreads();   // staging writes visible before phase-2 reads

    // ---- phase 2: 4-region projection; W2 from LDS (f16 pairs), C via s_load, sw via readlane ----
    {
        const int c = tid;
        const float* Cw = (const float*)ws;   // C[r*64 + ch], uniform addresses
        float acc[4][4];
        #pragma unroll
        for (int s = 0; s < 4; ++s)
            #pragma unroll
            for (int r = 0; r < 4; ++r) acc[s][r] = 0.f;

        #pragma unroll 8
        for (int ch2 = 0; ch2 < 32; ++ch2) {
            const unsigned d = sW2[ch2*256 + c];           // 2-way bank alias = free
            const __half2 h2 = __builtin_bit_cast(__half2, d);
            const float wA = __low2float(h2);              // channel 2*ch2
            const float wB = __high2float(h2);             // channel 2*ch2+1
            const int chA = 2*ch2, chB = 2*ch2 + 1;
            const float k1A = Cw[chA], k2A = Cw[64 + chA], k3A = Cw[128 + chA];
            const float k1B = Cw[chB], k2B = Cw[64 + chB], k3B = Cw[128 + chB];
            {
                const float s0 = rl(swv0, chA), s1 = rl(swv1, chA);
                const float s2 = rl(swv2, chA), s3 = rl(swv3, chA);
                const float t0 = s0*wA, t1 = s1*wA, t2 = s2*wA, t3 = s3*wA;
                acc[0][0] += t0; acc[0][1] = fmaf(t0,k1A,acc[0][1]); acc[0][2] = fmaf(t0,k2A,acc[0][2]); acc[0][3] = fmaf(t0,k3A,acc[0][3]);
                acc[1][0] += t1; acc[1][1] = fmaf(t1,k1A,acc[1][1]); acc[1][2] = fmaf(t1,k2A,acc[1][2]); acc[1][3] = fmaf(t1,k3A,acc[1][3]);
                acc[2][0] += t2; acc[2][1] = fmaf(t2,k1A,acc[2][1]); acc[2][2] = fmaf(t2,k2A,acc[2][2]); acc[2][3] = fmaf(t2,k3A,acc[2][3]);
                acc[3][0] += t3; acc[3][1] = fmaf(t3,k1A,acc[3][1]); acc[3][2] = fmaf(t3,k2A,acc[3][2]); acc[3][3] = fmaf(t3,k3A,acc[3][3]);
            }
            {
                const float s0 = rl(swv0, chB), s1 = rl(swv1, chB);
                const float s2 = rl(swv2, chB), s3 = rl(swv3, chB);
                const float t0 = s0*wB, t1 = s1*wB, t2 = s2*wB, t3 = s3*wB;
                acc[0][0] += t0; acc[0][1] = fmaf(t0,k1B,acc[0][1]); acc[0][2] = fmaf(t0,k2B,acc[0][2]); acc[0][3] = fmaf(t0,k3B,acc[0][3]);
                acc[1][0] += t1; acc[1][1] = fmaf(t1,k1B,acc[1][1]); acc[1][2] = fmaf(t1,k2B,acc[1][2]); acc[1][3] = fmaf(t1,k3B,acc[1][3]);
                acc[2][0] += t2; acc[2][1] = fmaf(t2,k1B,acc[2][1]); acc[2][2] = fmaf(t2,k2B,acc[2][2]); acc[2][3] = fmaf(t2,k3B,acc[2][3]);
                acc[3][0] += t3; acc[3][1] = fmaf(t3,k1B,acc[3][1]); acc[3][2] = fmaf(t3,k2B,acc[3][2]); acc[3][3] = fmaf(t3,k3B,acc[3][3]);
            }
        }

        // mixer (params uniform -> scalarized loads)
        const float mwa = mixwa[0], mwb = mixwb[0], mb2 = mixb2[0];
        const float bb2 = embb2[c];
        #pragma unroll
        for (int s = 0; s < 4; ++s) {
            const float f0 = acc[s][0]+bb2, f1 = acc[s][1]+bb2;
            const float f2 = acc[s][2]+bb2, f3 = acc[s][3]+bb2;
            float ev = mb2;
            #pragma unroll
            for (int j = 0; j < 8; ++j) {
                float p = fmaf(f0, mixW1[j],
                          fmaf(f1, mixW1[8 + j],
                          fmaf(f2, mixW1[16 + j],
                          fmaf(f3, mixW1[24 + j], mixb1[j]))));
                ev = fmaf(mwa*__sinf(p) + mwb*__cosf(p), mixW2[j], ev);
            }
            se[s][c] = ev;
        }
    }
    __syncthreads();

    // ---- phase 3: wave wv owns sample wv; barrier-free head ----
    const int f = lane, n = wv;
    float h;
    {   // layer 0: 256 -> 64, bf16-pair weights, 4-way ILP accumulators
        const unsigned* W0p = ws + WS_W0P;
        float p0 = 0.f, p1 = 0.f, p2 = 0.f, p3 = 0.f;
        #pragma unroll 16
        for (int j = 0; j < 64; ++j) {               // acts k = 4j..4j+3
            const float4 a4 = *(const float4*)&se[n][4*j];   // wave-uniform broadcast
            const unsigned d0 = W0p[(2*j)*64 + f];
            const unsigned d1 = W0p[(2*j+1)*64 + f];
            p0 = fmaf(a4.x, blo(d0), p0); p1 = fmaf(a4.y, bhi(d0), p1);
            p2 = fmaf(a4.z, blo(d1), p2); p3 = fmaf(a4.w, bhi(d1), p3);
        }
        const float a = (p0 + p1) + (p2 + p3) + outb0[f];
        h = outwa0[0]*__sinf(a) + outwb0[0]*__cosf(a);
    }

    #pragma unroll
    for (int i = 0; i < 4; ++i) {                    // 3 hidden + f1, barrier-free via readlane
        const unsigned* Wp = (i < 3) ? (ws + WS_WHP + i*2048) : (ws + WS_WF1P);
        float p0 = 0.f, p1 = 0.f;
        #pragma unroll
        for (int j = 0; j < 32; ++j) {               // acts k = 2j, 2j+1
            const unsigned d = Wp[j*64 + f];
            const float hk0 = rl(h, 2*j), hk1 = rl(h, 2*j + 1);
            p0 = fmaf(hk0, blo(d), p0);
            p1 = fmaf(hk1, bhi(d), p1);
        }
        float a = p0 + p1;
        float wa, wb;
        if (i < 3) { a += outbh[i*64 + f]; wa = outwah[i]; wb = outwbh[i]; }
        else       { a += outbf1[f];       wa = outwaf[0]; wb = outwbf[0]; }
        h = wa*__sinf(a) + wb*__cosf(a);
    }

    // final 64 -> 3 (wave-local LDS stage; no barrier needed, same wave)
    hfin[n][f] = h;
    if (f < 3) {
        float a = outbf2[f];
        #pragma unroll 16
        for (int k = 0; k < 64; ++k)
            a = fmaf(hfin[n][k], outWf2[k*3 + f], a);
        const int gn = n0 + n;
        if (gn < N) out[gn*3 + f] = a;
    }
}

extern "C" void kernel_launch(void* const* d_in, const int* in_sizes, int n_in,
                              void* d_out, int out_size, void* d_ws, size_t ws_size,
                              hipStream_t stream) {
    const float* x      = (const float*)d_in[0];
    const float* y      = (const float*)d_in[1];
    const float* t      = (const float*)d_in[2];
    const float* embW1  = (const float*)d_in[3];
    const float* embb1  = (const float*)d_in[4];
    const float* embwa  = (const float*)d_in[5];
    const float* embwb  = (const float*)d_in[6];
    const float* embW2  = (const float*)d_in[7];
    const float* embb2  = (const float*)d_in[8];
    const float* mixW1  = (const float*)d_in[9];
    const float* mixb1  = (const float*)d_in[10];
    const float* mixwa  = (const float*)d_in[11];
    const float* mixwb  = (const float*)d_in[12];
    const float* mixW2  = (const float*)d_in[13];
    const float* mixb2  = (const float*)d_in[14];
    const float* outW0  = (const float*)d_in[15];
    const float* outb0  = (const float*)d_in[16];
    const float* outwa0 = (const float*)d_in[17];
    const float* outwb0 = (const float*)d_in[18];
    const float* outWh  = (const float*)d_in[19];
    const float* outbh  = (const float*)d_in[20];
    const float* outwah = (const float*)d_in[21];
    const float* outwbh = (const float*)d_in[22];
    const float* outWf1 = (const float*)d_in[23];
    const float* outbf1 = (const float*)d_in[24];
    const float* outwaf = (const float*)d_in[25];
    const float* outwbf = (const float*)d_in[26];
    const float* outWf2 = (const float*)d_in[27];
    const float* outbf2 = (const float*)d_in[28];
    float* out = (float*)d_out;
    unsigned* ws = (unsigned*)d_ws;

    const int N = in_sizes[0];

    preprocess<<<97, 256, 0, stream>>>(embW1, embW2, outW0, outWh, outWf1, ws);

    const int blocks = (N + SPB - 1) / SPB;
    model_fused<<<blocks, 256, 0, stream>>>(
        x, y, t,
        embW1, embb1, embwa, embwb, embb2,
        mixW1, mixb1, mixwa, mixwb, mixW2, mixb2,
        outb0, outwa0, outwb0,
        outbh, outwah, outwbh,
        outbf1, outwaf, outwbf, outWf2, outbf2,
        ws, out, N);
}

// Round 7
// 126.233 us; speedup vs baseline: 1.1517x; 1.1517x over previous
//
#include <hip/hip_runtime.h>

typedef _Float16 f16;
typedef _Float16 f16x8 __attribute__((ext_vector_type(8)));
typedef float v4f __attribute__((ext_vector_type(4)));

// ws layout, f16 units from base:
// [0..16383]      W2T [c=256][k=64]
// [16384..32767]  W0T [f=64][k=256]
// [32768..45055]  WhT [3][f=64][k=64]
// [45056..49151]  Wf1T[f=64][k=64]
// then f32 C[3][64] at dword offset 24576 (byte 98304)
#define WS_W2T  0
#define WS_W0T  16384
#define WS_WHT  32768
#define WS_WF1T 45056
#define WS_CDW  24576

__global__ __launch_bounds__(256) void preprocess(
    const float* __restrict__ embW1, const float* __restrict__ embW2,
    const float* __restrict__ outW0, const float* __restrict__ outWh,
    const float* __restrict__ outWf1, f16* __restrict__ wsh)
{
    const int g = blockIdx.x * 256 + threadIdx.x;
    if (g < 16384) {                       // W2T[c][k] = embW2[k][c]
        const int c = g >> 6, k = g & 63;
        wsh[WS_W2T + g] = (f16)embW2[k*256 + c];
    } else if (g < 32768) {                // W0T[f][k] = outW0[k][f]
        const int i = g - 16384;
        const int f = i >> 8, k = i & 255;
        wsh[WS_W0T + i] = (f16)outW0[k*64 + f];
    } else if (g < 45056) {                // WhT[l][f][k] = outWh[l][k][f]
        const int i = g - 32768;
        const int l = i >> 12, f = (i >> 6) & 63, k = i & 63;
        wsh[WS_WHT + i] = (f16)outWh[l*4096 + k*64 + f];
    } else if (g < 49152) {                // Wf1T[f][k] = outWf1[k][f]
        const int i = g - 45056;
        const int f = i >> 6, k = i & 63;
        wsh[WS_WF1T + i] = (f16)outWf1[k*64 + f];
    } else if (g < 49344) {                // C region factors (symmetric grid collapse)
        const int i = g - 49152;
        const int r = i >> 6, ch = i & 63;
        const float w0 = embW1[ch], w1 = embW1[64 + ch], w2 = embW1[128 + ch];
        float v;
        if (r == 0) {
            v = (1.f + 2.f*__cosf(0.01f*w0)) * (1.f + 2.f*__cosf(0.01f*w1))
              * (1.f + 2.f*__cosf(0.01f*w2)) * (1.f/27.f);
        } else if (r == 1) {
            v = (1.f + 2.f*(__cosf(0.025f*w0) + __cosf(0.05f*w0)))
              * (1.f + 2.f*(__cosf(0.025f*w1) + __cosf(0.05f*w1)))
              * (1.f + 2.f*(__cosf(0.025f*w2) + __cosf(0.05f*w2))) * (1.f/125.f);
        } else {
            v = (1.f + 2.f*(__cosf(0.03f*w0) + __cosf(0.06f*w0) + __cosf(0.09f*w0)))
              * (1.f + 2.f*(__cosf(0.03f*w1) + __cosf(0.06f*w1) + __cosf(0.09f*w1)))
              * (1.f + 2.f*(__cosf(0.03f*w2) + __cosf(0.06f*w2) + __cosf(0.09f*w2))) * (1.f/343.f);
        }
        ((float*)wsh)[WS_CDW + i] = v;
    }
}

__global__ __launch_bounds__(256) void model_mfma(
    const float* __restrict__ x, const float* __restrict__ y, const float* __restrict__ t,
    const float* __restrict__ embW1, const float* __restrict__ embb1,
    const float* __restrict__ embwa, const float* __restrict__ embwb,
    const float* __restrict__ embb2,
    const float* __restrict__ mixW1, const float* __restrict__ mixb1,
    const float* __restrict__ mixwa, const float* __restrict__ mixwb,
    const float* __restrict__ mixW2, const float* __restrict__ mixb2,
    const float* __restrict__ outb0,
    const float* __restrict__ outwa0, const float* __restrict__ outwb0,
    const float* __restrict__ outbh,
    const float* __restrict__ outwah, const float* __restrict__ outwbh,
    const float* __restrict__ outbf1,
    const float* __restrict__ outwaf, const float* __restrict__ outwbf,
    const float* __restrict__ outWf2, const float* __restrict__ outbf2,
    const f16* __restrict__ wsh,
    float* __restrict__ out, int N)
{
    // padded rows: W2T/sA/sH +8 f16, sE +8 f16, sHf +1 f32 (bank-conflict rotation,
    // keeps every f16x8 base 16B-aligned)
    __shared__ __attribute__((aligned(16))) f16 sW2T[256*72];   // 36 KB [c][k]
    __shared__ __attribute__((aligned(16))) f16 sA[64*72];      //  9 KB [m=s*4+r][k]
    __shared__ __attribute__((aligned(16))) f16 sE[16*264];     //  8.25 KB [s][c]
    __shared__ __attribute__((aligned(16))) f16 sH[2][16*72];   //  4.5 KB [s][f]
    __shared__ float sHf[16*65];                                //  4.06 KB

    const int tid  = threadIdx.x;
    const int lane = tid & 63;
    const int wv   = tid >> 6;
    const int n0   = blockIdx.x * 16;

    // ---- stage W2T into LDS (1 row per thread, 8 x uint4) ----
    {
        const uint4* src = (const uint4*)(wsh + WS_W2T + tid*64);
        uint4* dst = (uint4*)(sW2T + tid*72);
        #pragma unroll
        for (int i = 0; i < 8; ++i) dst[i] = src[i];
    }

    // ---- phase 1: build A[m][k] = sw[s][k] * C_r[k] (f16) ----
    {
        const int k = tid & 63;
        const int sq = tid >> 6;
        const float w0 = embW1[k], w1 = embW1[64+k], w2 = embW1[128+k];
        const float b1 = embb1[k];
        const float ewa = embwa[0], ewb = embwb[0];
        const float* Cw = (const float*)wsh + WS_CDW;
        const float c1 = Cw[k], c2 = Cw[64+k], c3 = Cw[128+k];
        #pragma unroll
        for (int q = 0; q < 4; ++q) {
            const int s = sq*4 + q;
            const int ns = (n0 + s < N) ? (n0 + s) : (N - 1);
            const float u = fmaf(x[ns], w0, fmaf(y[ns], w1, fmaf(t[ns], w2, b1)));
            const float sv = ewa*__sinf(u) + ewb*__cosf(u);
            f16* row = sA + (s*4)*72 + k;
            row[0]   = (f16)sv;
            row[72]  = (f16)(sv*c1);
            row[144] = (f16)(sv*c2);
            row[216] = (f16)(sv*c3);
        }
    }
    __syncthreads();

    const int l15 = lane & 15, qb = lane >> 4;

    // ---- phase 2: [64 x 64] @ W2 [64 x 256] via MFMA; wave wv owns M-tile wv ----
    // C/D layout: col = lane&15, row = (lane>>4)*4 + reg  ->  lane holds all 4
    // regions of sample s_loc = 4*wv + qb at column c -> mixer entirely in regs.
    {
        const f16x8 af0 = *(const f16x8*)(sA + (16*wv + l15)*72 + qb*8);
        const f16x8 af1 = *(const f16x8*)(sA + (16*wv + l15)*72 + 32 + qb*8);
        const int s_loc = 4*wv + qb;
        const float mwa = mixwa[0], mwb = mixwb[0], mb2v = mixb2[0];
        #pragma unroll
        for (int nt = 0; nt < 16; ++nt) {
            const f16x8 bf0 = *(const f16x8*)(sW2T + (16*nt + l15)*72 + qb*8);
            const f16x8 bf1 = *(const f16x8*)(sW2T + (16*nt + l15)*72 + 32 + qb*8);
            v4f acc = {0.f, 0.f, 0.f, 0.f};
            acc = __builtin_amdgcn_mfma_f32_16x16x32_f16(af0, bf0, acc, 0, 0, 0);
            acc = __builtin_amdgcn_mfma_f32_16x16x32_f16(af1, bf1, acc, 0, 0, 0);
            const int c = 16*nt + l15;
            const float b2c = embb2[c];
            const float s0 = acc[0]+b2c, s1 = acc[1]+b2c, s2 = acc[2]+b2c, s3 = acc[3]+b2c;
            float ev = mb2v;
            #pragma unroll
            for (int j = 0; j < 8; ++j) {
                float p = fmaf(s0, mixW1[j],
                          fmaf(s1, mixW1[8+j],
                          fmaf(s2, mixW1[16+j],
                          fmaf(s3, mixW1[24+j], mixb1[j]))));
                ev = fmaf(mwa*__sinf(p) + mwb*__cosf(p), mixW2[j], ev);
            }
            sE[s_loc*264 + c] = (f16)ev;
        }
    }
    __syncthreads();

    // ---- phase 3: head. wave wv owns feature tile f = 16*wv + l15 ----
    const int fme = 16*wv + l15;

    // layer 0: [16 x 256] @ [256 x 64]
    {
        v4f acc = {0.f, 0.f, 0.f, 0.f};
        const f16* Ae   = sE + l15*264 + qb*8;
        const f16* W0Tg = wsh + WS_W0T + fme*256 + qb*8;
        #pragma unroll
        for (int kt = 0; kt < 8; ++kt) {
            const f16x8 af = *(const f16x8*)(Ae + kt*32);
            const f16x8 bf = *(const f16x8*)(W0Tg + kt*32);
            acc = __builtin_amdgcn_mfma_f32_16x16x32_f16(af, bf, acc, 0, 0, 0);
        }
        const float b0 = outb0[fme], wa = outwa0[0], wb = outwb0[0];
        #pragma unroll
        for (int r = 0; r < 4; ++r) {
            const float a = acc[r] + b0;
            sH[0][(qb*4 + r)*72 + fme] = (f16)(wa*__sinf(a) + wb*__cosf(a));
        }
    }
    __syncthreads();

    // hidden x3 + f1: [16 x 64] @ [64 x 64]
    int cur = 0;
    #pragma unroll
    for (int i = 0; i < 4; ++i) {
        const f16* Wg = (i < 3) ? (wsh + WS_WHT + i*4096) : (wsh + WS_WF1T);
        v4f acc = {0.f, 0.f, 0.f, 0.f};
        #pragma unroll
        for (int kt = 0; kt < 2; ++kt) {
            const f16x8 af = *(const f16x8*)(sH[cur] + l15*72 + kt*32 + qb*8);
            const f16x8 bf = *(const f16x8*)(Wg + fme*64 + kt*32 + qb*8);
            acc = __builtin_amdgcn_mfma_f32_16x16x32_f16(af, bf, acc, 0, 0, 0);
        }
        float bias, wa, wb;
        if (i < 3) { bias = outbh[i*64 + fme]; wa = outwah[i]; wb = outwbh[i]; }
        else       { bias = outbf1[fme];       wa = outwaf[0]; wb = outwbf[0]; }
        #pragma unroll
        for (int r = 0; r < 4; ++r) {
            const float a = acc[r] + bias;
            const float v = wa*__sinf(a) + wb*__cosf(a);
            if (i < 3) sH[cur^1][(qb*4 + r)*72 + fme] = (f16)v;
            else       sHf[(qb*4 + r)*65 + fme] = v;
        }
        __syncthreads();
        cur ^= 1;
    }

    // ---- final 64 -> 3 ----
    if (tid < 48) {
        const int s = tid / 3, o = tid - s*3;
        float a = outbf2[o];
        #pragma unroll 16
        for (int k = 0; k < 64; ++k)
            a = fmaf(sHf[s*65 + k], outWf2[k*3 + o], a);
        const int gn = n0 + s;
        if (gn < N) out[gn*3 + o] = a;
    }
}

extern "C" void kernel_launch(void* const* d_in, const int* in_sizes, int n_in,
                              void* d_out, int out_size, void* d_ws, size_t ws_size,
                              hipStream_t stream) {
    const float* x      = (const float*)d_in[0];
    const float* y      = (const float*)d_in[1];
    const float* t      = (const float*)d_in[2];
    const float* embW1  = (const float*)d_in[3];
    const float* embb1  = (const float*)d_in[4];
    const float* embwa  = (const float*)d_in[5];
    const float* embwb  = (const float*)d_in[6];
    const float* embW2  = (const float*)d_in[7];
    const float* embb2  = (const float*)d_in[8];
    const float* mixW1  = (const float*)d_in[9];
    const float* mixb1  = (const float*)d_in[10];
    const float* mixwa  = (const float*)d_in[11];
    const float* mixwb  = (const float*)d_in[12];
    const float* mixW2  = (const float*)d_in[13];
    const float* mixb2  = (const float*)d_in[14];
    const float* outW0  = (const float*)d_in[15];
    const float* outb0  = (const float*)d_in[16];
    const float* outwa0 = (const float*)d_in[17];
    const float* outwb0 = (const float*)d_in[18];
    const float* outWh  = (const float*)d_in[19];
    const float* outbh  = (const float*)d_in[20];
    const float* outwah = (const float*)d_in[21];
    const float* outwbh = (const float*)d_in[22];
    const float* outWf1 = (const float*)d_in[23];
    const float* outbf1 = (const float*)d_in[24];
    const float* outwaf = (const float*)d_in[25];
    const float* outwbf = (const float*)d_in[26];
    const float* outWf2 = (const float*)d_in[27];
    const float* outbf2 = (const float*)d_in[28];
    float* out = (float*)d_out;
    f16* wsh = (f16*)d_ws;

    const int N = in_sizes[0];

    preprocess<<<193, 256, 0, stream>>>(embW1, embW2, outW0, outWh, outWf1, wsh);

    const int blocks = (N + 15) / 16;
    model_mfma<<<blocks, 256, 0, stream>>>(
        x, y, t,
        embW1, embb1, embwa, embwb, embb2,
        mixW1, mixb1, mixwa, mixwb, mixW2, mixb2,
        outb0, outwa0, outwb0,
        outbh, outwah, outwbh,
        outbf1, outwaf, outwbf, outWf2, outbf2,
        wsh, out, N);
}

// Round 9
// 125.988 us; speedup vs baseline: 1.1539x; 1.0019x over previous
//
#include <hip/hip_runtime.h>

typedef _Float16 f16;
typedef _Float16 f16x8 __attribute__((ext_vector_type(8)));
typedef float v4f __attribute__((ext_vector_type(4)));

// ws layout, f16 units from base:
// [0..16383]      W2T [c=256][k=64]
// [16384..32767]  W0T [f=64][k=256]
// [32768..45055]  WhT [3][f=64][k=64]
// [45056..49151]  Wf1T[f=64][k=64]
// f32 C[3][64] at dword 24576; f32 RPHI[14] at dword 24768
#define WS_W2T  0
#define WS_W0T  16384
#define WS_WHT  32768
#define WS_WF1T 45056
#define WS_CDW  24576
#define WS_RPHI 24768

__global__ __launch_bounds__(256) void preprocess(
    const float* __restrict__ embW1, const float* __restrict__ embW2,
    const float* __restrict__ outW0, const float* __restrict__ outWh,
    const float* __restrict__ outWf1,
    const float* __restrict__ embwa, const float* __restrict__ embwb,
    const float* __restrict__ mixwa, const float* __restrict__ mixwb,
    const float* __restrict__ outwa0, const float* __restrict__ outwb0,
    const float* __restrict__ outwah, const float* __restrict__ outwbh,
    const float* __restrict__ outwaf, const float* __restrict__ outwbf,
    f16* __restrict__ wsh)
{
    const int g = blockIdx.x * 256 + threadIdx.x;
    if (g < 16384) {                       // W2T[c][k] = embW2[k][c]
        const int c = g >> 6, k = g & 63;
        wsh[WS_W2T + g] = (f16)embW2[k*256 + c];
    } else if (g < 32768) {                // W0T[f][k] = outW0[k][f]
        const int i = g - 16384;
        const int f = i >> 8, k = i & 255;
        wsh[WS_W0T + i] = (f16)outW0[k*64 + f];
    } else if (g < 45056) {                // WhT[l][f][k] = outWh[l][k][f]
        const int i = g - 32768;
        const int l = i >> 12, f = (i >> 6) & 63, k = i & 63;
        wsh[WS_WHT + i] = (f16)outWh[l*4096 + k*64 + f];
    } else if (g < 49152) {                // Wf1T[f][k] = outWf1[k][f]
        const int i = g - 45056;
        const int f = i >> 6, k = i & 63;
        wsh[WS_WF1T + i] = (f16)outWf1[k*64 + f];
    } else if (g < 49344) {                // C region factors (symmetric grid collapse)
        const int i = g - 49152;
        const int r = i >> 6, ch = i & 63;
        const float w0 = embW1[ch], w1 = embW1[64 + ch], w2 = embW1[128 + ch];
        float v;
        if (r == 0) {
            v = (1.f + 2.f*__cosf(0.01f*w0)) * (1.f + 2.f*__cosf(0.01f*w1))
              * (1.f + 2.f*__cosf(0.01f*w2)) * (1.f/27.f);
        } else if (r == 1) {
            v = (1.f + 2.f*(__cosf(0.025f*w0) + __cosf(0.05f*w0)))
              * (1.f + 2.f*(__cosf(0.025f*w1) + __cosf(0.05f*w1)))
              * (1.f + 2.f*(__cosf(0.025f*w2) + __cosf(0.05f*w2))) * (1.f/125.f);
        } else {
            v = (1.f + 2.f*(__cosf(0.03f*w0) + __cosf(0.06f*w0) + __cosf(0.09f*w0)))
              * (1.f + 2.f*(__cosf(0.03f*w1) + __cosf(0.06f*w1) + __cosf(0.09f*w1)))
              * (1.f + 2.f*(__cosf(0.03f*w2) + __cosf(0.06f*w2) + __cosf(0.09f*w2))) * (1.f/343.f);
        }
        ((float*)wsh)[WS_CDW + i] = v;
    } else if (g < 49360) {                // RPHI: wa*sin(u)+wb*cos(u) = R*sin(u+phi)
        const int i = g - 49344;
        const int p = i >> 1;
        float wa, wb;
        switch (p) {
            case 0: wa = embwa[0];  wb = embwb[0];  break;
            case 1: wa = mixwa[0];  wb = mixwb[0];  break;
            case 2: wa = outwa0[0]; wb = outwb0[0]; break;
            case 3: case 4: case 5: wa = outwah[p-3]; wb = outwbh[p-3]; break;
            default: wa = outwaf[0]; wb = outwbf[0]; break;
        }
        const float v = (i & 1) ? atan2f(wb, wa) : sqrtf(wa*wa + wb*wb);
        ((float*)wsh)[WS_RPHI + p*2 + (i & 1)] = v;
    }
}

__global__ __launch_bounds__(256, 4) void model_mfma(
    const float* __restrict__ x, const float* __restrict__ y, const float* __restrict__ t,
    const float* __restrict__ embW1, const float* __restrict__ embb1,
    const float* __restrict__ embb2,
    const float* __restrict__ mixW1, const float* __restrict__ mixb1,
    const float* __restrict__ mixW2, const float* __restrict__ mixb2,
    const float* __restrict__ outb0, const float* __restrict__ outbh,
    const float* __restrict__ outbf1,
    const float* __restrict__ outWf2, const float* __restrict__ outbf2,
    const f16* __restrict__ wsh,
    float* __restrict__ out, int N)
{
    __shared__ __attribute__((aligned(16))) f16 sA[16*72];     // [m=s*4+r][k]
    __shared__ __attribute__((aligned(16))) f16 sE[16*264];    // [s][c] rows 0-3 valid
    __shared__ __attribute__((aligned(16))) f16 sH[2][16*72];  // [s][f] rows 0-3 valid
    __shared__ float sHf[4*65];

    const int tid  = threadIdx.x;
    const int lane = tid & 63;
    const int wv   = tid >> 6;
    const int n0   = blockIdx.x * 4;
    const float* rphi = (const float*)wsh + WS_RPHI;

    // ---- phase 1: wave sq computes sample sq; lane = channel k ----
    {
        const int k = lane, sq = wv;
        const float w0 = embW1[k], w1 = embW1[64+k], w2 = embW1[128+k];
        const float b1 = embb1[k];
        const float* Cw = (const float*)wsh + WS_CDW;
        const float c1 = Cw[k], c2 = Cw[64+k], c3 = Cw[128+k];
        const int ns = (n0 + sq < N) ? (n0 + sq) : (N - 1);
        const float u = fmaf(x[ns], w0, fmaf(y[ns], w1, fmaf(t[ns], w2, b1)));
        const float sv = rphi[0] * __sinf(u + rphi[1]);
        f16* row = sA + (sq*4)*72 + k;
        row[0]   = (f16)sv;
        row[72]  = (f16)(sv*c1);
        row[144] = (f16)(sv*c2);
        row[216] = (f16)(sv*c3);
    }
    __syncthreads();

    const int l15 = lane & 15, qb = lane >> 4;

    // ---- phase 2: [16 x 64] @ W2 [64 x 256]; wave wv owns cols wv*64..+63 ----
    // C/D: col=lane&15, row=qb*4+reg -> lane holds sample qb, all 4 regions.
    {
        const f16x8 af0 = *(const f16x8*)(sA + l15*72 + qb*8);
        const f16x8 af1 = *(const f16x8*)(sA + l15*72 + 32 + qb*8);
        const float mR = rphi[2], mP = rphi[3], mb2v = mixb2[0];
        #pragma unroll
        for (int nt = 0; nt < 4; ++nt) {
            const int cb = wv*64 + nt*16;
            const f16x8 bf0 = *(const f16x8*)(wsh + WS_W2T + (cb + l15)*64 + qb*8);
            const f16x8 bf1 = *(const f16x8*)(wsh + WS_W2T + (cb + l15)*64 + 32 + qb*8);
            v4f acc = {0.f, 0.f, 0.f, 0.f};
            acc = __builtin_amdgcn_mfma_f32_16x16x32_f16(af0, bf0, acc, 0, 0, 0);
            acc = __builtin_amdgcn_mfma_f32_16x16x32_f16(af1, bf1, acc, 0, 0, 0);
            const int c = cb + l15;
            const float b2c = embb2[c];
            const float s0 = acc[0]+b2c, s1 = acc[1]+b2c, s2 = acc[2]+b2c, s3 = acc[3]+b2c;
            float ev = mb2v;
            #pragma unroll
            for (int j = 0; j < 8; ++j) {
                float p = fmaf(s0, mixW1[j],
                          fmaf(s1, mixW1[8+j],
                          fmaf(s2, mixW1[16+j],
                          fmaf(s3, mixW1[24+j], mixb1[j]))));
                ev = fmaf(mR*__sinf(p + mP), mixW2[j], ev);
            }
            sE[qb*264 + c] = (f16)ev;
        }
    }
    __syncthreads();

    // ---- phase 3: wave wv owns feature tile fme = wv*16 + l15 ----
    const int fme = wv*16 + l15;

    // layer 0: [4 x 256] @ [256 x 64] (A rows 4-15 garbage -> rows only affect
    // their own D rows; store qb==0 only)
    {
        v4f acc = {0.f, 0.f, 0.f, 0.f};
        const f16* Ae   = sE + l15*264 + qb*8;
        const f16* W0Tg = wsh + WS_W0T + fme*256 + qb*8;
        #pragma unroll
        for (int kt = 0; kt < 8; ++kt) {
            const f16x8 af = *(const f16x8*)(Ae + kt*32);
            const f16x8 bf = *(const f16x8*)(W0Tg + kt*32);
            acc = __builtin_amdgcn_mfma_f32_16x16x32_f16(af, bf, acc, 0, 0, 0);
        }
        if (qb == 0) {
            const float b0 = outb0[fme], R = rphi[4], P = rphi[5];
            #pragma unroll
            for (int r = 0; r < 4; ++r)
                sH[0][r*72 + fme] = (f16)(R*__sinf(acc[r] + b0 + P));
        }
    }
    __syncthreads();

    // hidden x3 + f1: [4 x 64] @ [64 x 64]
    int cur = 0;
    #pragma unroll
    for (int i = 0; i < 4; ++i) {
        const f16* Wg = (i < 3) ? (wsh + WS_WHT + i*4096) : (wsh + WS_WF1T);
        v4f acc = {0.f, 0.f, 0.f, 0.f};
        #pragma unroll
        for (int kt = 0; kt < 2; ++kt) {
            const f16x8 af = *(const f16x8*)(sH[cur] + l15*72 + kt*32 + qb*8);
            const f16x8 bf = *(const f16x8*)(Wg + fme*64 + kt*32 + qb*8);
            acc = __builtin_amdgcn_mfma_f32_16x16x32_f16(af, bf, acc, 0, 0, 0);
        }
        if (qb == 0) {
            float bias, R, P;
            if (i < 3) { bias = outbh[i*64 + fme]; R = rphi[6+2*i]; P = rphi[7+2*i]; }
            else       { bias = outbf1[fme];       R = rphi[12];    P = rphi[13]; }
            #pragma unroll
            for (int r = 0; r < 4; ++r) {
                const float v = R*__sinf(acc[r] + bias + P);
                if (i < 3) sH[cur^1][r*72 + fme] = (f16)v;
                else       sHf[r*65 + fme] = v;
            }
        }
        __syncthreads();
        cur ^= 1;
    }

    // ---- final 64 -> 3 ----
    if (tid < 12) {
        const int s = tid / 3, o = tid - s*3;
        float a = outbf2[o];
        #pragma unroll 16
        for (int k = 0; k < 64; ++k)
            a = fmaf(sHf[s*65 + k], outWf2[k*3 + o], a);
        const int gn = n0 + s;
        if (gn < N) out[gn*3 + o] = a;
    }
}

extern "C" void kernel_launch(void* const* d_in, const int* in_sizes, int n_in,
                              void* d_out, int out_size, void* d_ws, size_t ws_size,
                              hipStream_t stream) {
    const float* x      = (const float*)d_in[0];
    const float* y      = (const float*)d_in[1];
    const float* t      = (const float*)d_in[2];
    const float* embW1  = (const float*)d_in[3];
    const float* embb1  = (const float*)d_in[4];
    const float* embwa  = (const float*)d_in[5];
    const float* embwb  = (const float*)d_in[6];
    const float* embW2  = (const float*)d_in[7];
    const float* embb2  = (const float*)d_in[8];
    const float* mixW1  = (const float*)d_in[9];
    const float* mixb1  = (const float*)d_in[10];
    const float* mixwa  = (const float*)d_in[11];
    const float* mixwb  = (const float*)d_in[12];
    const float* mixW2  = (const float*)d_in[13];
    const float* mixb2  = (const float*)d_in[14];
    const float* outW0  = (const float*)d_in[15];
    const float* outb0  = (const float*)d_in[16];
    const float* outwa0 = (const float*)d_in[17];
    const float* outwb0 = (const float*)d_in[18];
    const float* outWh  = (const float*)d_in[19];
    const float* outbh  = (const float*)d_in[20];
    const float* outwah = (const float*)d_in[21];
    const float* outwbh = (const float*)d_in[22];
    const float* outWf1 = (const float*)d_in[23];
    const float* outbf1 = (const float*)d_in[24];
    const float* outwaf = (const float*)d_in[25];
    const float* outwbf = (const float*)d_in[26];
    const float* outWf2 = (const float*)d_in[27];
    const float* outbf2 = (const float*)d_in[28];
    float* out = (float*)d_out;
    f16* wsh = (f16*)d_ws;

    const int N = in_sizes[0];

    preprocess<<<193, 256, 0, stream>>>(embW1, embW2, outW0, outWh, outWf1,
                                        embwa, embwb, mixwa, mixwb,
                                        outwa0, outwb0, outwah, outwbh,
                                        outwaf, outwbf, wsh);

    const int blocks = (N + 3) / 4;
    model_mfma<<<blocks, 256, 0, stream>>>(
        x, y, t,
        embW1, embb1, embb2,
        mixW1, mixb1, mixW2, mixb2,
        outb0, outbh, outbf1, outWf2, outbf2,
        wsh, out, N);
}